// Round 8
// baseline (2702.496 us; speedup 1.0000x reference)
//
#include <hip/hip_runtime.h>
#include <hip/hip_bf16.h>
#include <stdint.h>

typedef __hip_bfloat16 bf16s;                                    // storage type
typedef __bf16 bf16x8 __attribute__((ext_vector_type(8)));       // MFMA operand
typedef float  floatx4 __attribute__((ext_vector_type(4)));      // MFMA acc

#define BM 256
#define BN 256
#define BK 32

__device__ __forceinline__ void gload_lds16(const void* g, void* l) {
    auto* gp = reinterpret_cast<const __attribute__((address_space(1))) uint32_t*>(
        reinterpret_cast<uintptr_t>(g));
    auto* lp = reinterpret_cast<__attribute__((address_space(3))) uint32_t*>(
        reinterpret_cast<uintptr_t>(l));
    __builtin_amdgcn_global_load_lds(gp, lp, 16, 0, 0);
}

// ---------- x (f32) -> bf16, vectorized ----------
__global__ void cvt_f32_bf16(const float* __restrict__ x, bf16s* __restrict__ y, long n4) {
    long i = (long)blockIdx.x * blockDim.x + threadIdx.x;
    long stride = (long)gridDim.x * blockDim.x;
    for (; i < n4; i += stride) {
        float4 v = ((const float4*)x)[i];
        bf16s tmp[4];
        tmp[0] = __float2bfloat16(v.x);
        tmp[1] = __float2bfloat16(v.y);
        tmp[2] = __float2bfloat16(v.z);
        tmp[3] = __float2bfloat16(v.w);
        *(uint2*)&y[i * 4] = *(uint2*)tmp;
    }
}

// ---------- Wadj = W + lora_B @ lora_A, output bf16 ----------
__global__ void adjust_weight(const float* __restrict__ W, const float* __restrict__ lA,
                              const float* __restrict__ lB, bf16s* __restrict__ Wb,
                              int N, int Kd, int r) {
    long idx = (long)blockIdx.x * blockDim.x + threadIdx.x;
    int kq = Kd >> 2;
    long total = (long)N * kq;
    if (idx >= total) return;
    int n  = (int)(idx / kq);
    int k4 = (int)(idx - (long)n * kq) << 2;
    float4 w = *(const float4*)&W[(size_t)n * Kd + k4];
    float a0 = w.x, a1 = w.y, a2 = w.z, a3 = w.w;
    for (int j = 0; j < r; ++j) {
        float b = lB[n * r + j];
        float4 av = *(const float4*)&lA[(size_t)j * Kd + k4];
        a0 += b * av.x; a1 += b * av.y; a2 += b * av.z; a3 += b * av.w;
    }
    bf16s tmp[4];
    tmp[0] = __float2bfloat16(a0);
    tmp[1] = __float2bfloat16(a1);
    tmp[2] = __float2bfloat16(a2);
    tmp[3] = __float2bfloat16(a3);
    *(uint2*)&Wb[(size_t)n * Kd + k4] = *(uint2*)tmp;
}

// ==========================================================================
// 256x256 tile, BK=32, 8 waves (2M x 4N), 16x16x32 MFMA, 64 KiB LDS ->
// TWO blocks per CU (launch_bounds(512,4)). The two blocks form independent
// barrier domains: while one block is barrier-synced staging/reading, the
// other block's waves feed the matrix pipe — cross-block MFMA/LDS overlap
// that a single barrier-locked block can't achieve (r4/r5/r7 all pinned at
// MfmaUtil 46% = sum-not-overlap of matrix and LDS port time).
// Schedule per K-tile (one barrier): stage t+1 (4 gload_lds, linear dest,
// pre-swizzled source granule) | read 12 frags | 32 independent MFMA |
// vmcnt(0)+barrier. BK=32 => each acc touched once per tile (no dependent
// back-to-back MFMA).
// LDS granule swizzle: slot s of row l holds source granule s^((l>>1)&3);
// read slot c = kg^((lr>>1)&3). Audited: every 4-bank group serves exactly
// 8 lanes per ds_read_b128 => 0 extra cycles (conflict-free).
// ==========================================================================
__global__ __launch_bounds__(512, 4)
void gemm_2blk(const bf16s* __restrict__ A,   // [M,K] bf16
               const bf16s* __restrict__ B,   // [N,K] bf16
               const float* __restrict__ bias,
               float* __restrict__ C,         // [M,N] f32
               int M, int N, int K) {
    __shared__ __align__(16) bf16s lds[2][2][BM * BK];   // 2dbuf x (A,B) x 256x32 = 64 KiB

    const int nbn = N / BN;
    const int nwg = gridDim.x;
    int bid = blockIdx.x;
    int swz = bid;
    if ((nwg & 7) == 0) swz = (bid & 7) * (nwg >> 3) + (bid >> 3);   // XCD swizzle
    const int bm = swz / nbn, bn = swz % nbn;

    const int th   = threadIdx.x;
    const int lane = th & 63;
    const int wid  = th >> 6;
    const int wm = wid >> 2;           // 0..1 -> 128-row slice of C
    const int wn = wid & 3;            // 0..3 -> 64-col slice of C
    const int lr = lane & 15;
    const int kg = lane >> 4;          // 0..3: 8-elem K-granule

    const bf16s* gA = A + (size_t)(bm * BM) * K;
    const bf16s* gB = B + (size_t)(bn * BN) * K;
    const int NT = K / BK;             // 128

    floatx4 acc[8][4];
#pragma unroll
    for (int m = 0; m < 8; ++m)
#pragma unroll
        for (int n = 0; n < 4; ++n)
            acc[m][n] = (floatx4){0.f, 0.f, 0.f, 0.f};

    // ---- staging: fully linear LDS dest (slot = g*512+th), source granule
    // pre-swizzled so that slot s of row l holds granule s^((l>>1)&3).
    const int srow  = th >> 2;                       // row within 128-row group
    const int sgran = (th & 3) ^ ((th >> 3) & 3);    // pre-swizzled src granule

    auto stage = [&](int dbuf, int ab, const bf16s* gbase, int k0) {
#pragma unroll
        for (int g = 0; g < 2; ++g) {
            int l = g * 128 + srow;                  // global row 0..255
            gload_lds16(gbase + (size_t)l * K + k0 + sgran * 8,
                        &lds[dbuf][ab][((size_t)g * 512 + th) * 8]);
        }
    };

    // ---- fragment reads (global-row indexed, no permutation) ----
    auto ldA = [&](const bf16s* base, int mh, int mp) -> bf16x8 {
        int l = wm * 128 + mh * 64 + mp * 16 + lr;
        int c = kg ^ ((lr >> 1) & 3);
        return *(const bf16x8*)(base + l * BK + c * 8);
    };
    auto ldB = [&](const bf16s* base, int nh, int np) -> bf16x8 {
        int l = wn * 64 + nh * 32 + np * 16 + lr;
        int c = kg ^ ((lr >> 1) & 3);
        return *(const bf16x8*)(base + l * BK + c * 8);
    };

    // ---- prologue: stage tile 0, publish ----
    stage(0, 0, gA, 0);
    stage(0, 1, gB, 0);
    asm volatile("s_waitcnt vmcnt(0)" ::: "memory");
    asm volatile("s_barrier" ::: "memory");

    for (int t = 0; t < NT; ++t) {
        const bf16s* Ab = &lds[t & 1][0][0];
        const bf16s* Bb = &lds[t & 1][1][0];

        // issue staging for t+1 first (latency hides under this tile's work)
        if (t + 1 < NT) {
            const int k1 = (t + 1) * BK;
            stage((t + 1) & 1, 0, gA, k1);
            stage((t + 1) & 1, 1, gB, k1);
        }

        // read 12 fragments
        bf16x8 af[8], bfr[4];
#pragma unroll
        for (int mh = 0; mh < 2; ++mh)
#pragma unroll
            for (int mp = 0; mp < 4; ++mp)
                af[mh * 4 + mp] = ldA(Ab, mh, mp);
#pragma unroll
        for (int nh = 0; nh < 2; ++nh)
#pragma unroll
            for (int np = 0; np < 2; ++np)
                bfr[nh * 2 + np] = ldB(Bb, nh, np);

        // 32 independent MFMAs (each acc exactly once)
        __builtin_amdgcn_s_setprio(1);
#pragma unroll
        for (int m = 0; m < 8; ++m)
#pragma unroll
            for (int n = 0; n < 4; ++n)
                acc[m][n] = __builtin_amdgcn_mfma_f32_16x16x32_bf16(
                    af[m], bfr[n], acc[m][n], 0, 0, 0);
        __builtin_amdgcn_s_setprio(0);

        // boundary: publish tile t+1
        asm volatile("s_waitcnt vmcnt(0)" ::: "memory");
        asm volatile("s_barrier" ::: "memory");
    }

    // ---- epilogue: C/D layout col = lane&15, row = (lane>>4)*4 + q ----
    // m = mh*4+mp -> global row wm*128 + mh*64 + mp*16; n = nh*2+np -> col wn*64+nh*32+np*16
    const int crow = bm * BM + wm * 128;
    const int ccol = bn * BN + wn * 64;
#pragma unroll
    for (int n = 0; n < 4; ++n) {
        int col = ccol + n * 16 + lr;
        float bv = bias[col];
#pragma unroll
        for (int m = 0; m < 8; ++m) {
            int row0 = crow + m * 16 + kg * 4;
#pragma unroll
            for (int q = 0; q < 4; ++q)
                C[(size_t)(row0 + q) * N + col] = acc[m][n][q] + bv;
        }
    }
}

// ---------- fallback (f32, slow but correct) ----------
__global__ void xa_kernel(const float* __restrict__ x, const float* __restrict__ lA,
                          float* __restrict__ xa, long M, int K, int r) {
    long idx = (long)blockIdx.x * blockDim.x + threadIdx.x;
    long total = M * r;
    if (idx >= total) return;
    long m = idx / r; int j = (int)(idx % r);
    const float* xr = x + m * (long)K;
    const float* ar = lA + (size_t)j * K;
    float s = 0.f;
    for (int k = 0; k < K; k += 4) {
        float4 xv = *(const float4*)&xr[k];
        float4 av = *(const float4*)&ar[k];
        s += xv.x * av.x + xv.y * av.y + xv.z * av.z + xv.w * av.w;
    }
    xa[idx] = s;
}

__global__ void naive_out(const float* __restrict__ x, const float* __restrict__ W,
                          const float* __restrict__ bias, const float* __restrict__ xa,
                          const float* __restrict__ lB, float* __restrict__ out,
                          long M, int N, int K, int r) {
    long idx = (long)blockIdx.x * blockDim.x + threadIdx.x;
    long total = M * (long)N;
    if (idx >= total) return;
    long m = idx / N; int n = (int)(idx % N);
    const float* xr = x + m * (long)K;
    const float* wr = W + (size_t)n * K;
    float s = bias[n];
    for (int k = 0; k < K; k += 4) {
        float4 xv = *(const float4*)&xr[k];
        float4 wv = *(const float4*)&wr[k];
        s += xv.x * wv.x + xv.y * wv.y + xv.z * wv.z + xv.w * wv.w;
    }
    const float* xar = xa + m * r;
    const float* br  = lB + (size_t)n * r;
    for (int j = 0; j < r; ++j) s += xar[j] * br[j];
    out[idx] = s;
}

extern "C" void kernel_launch(void* const* d_in, const int* in_sizes, int n_in,
                              void* d_out, int out_size, void* d_ws, size_t ws_size,
                              hipStream_t stream) {
    const float* x    = (const float*)d_in[0];
    const float* W    = (const float*)d_in[1];
    const float* bias = (const float*)d_in[2];
    const float* lA   = (const float*)d_in[3];
    const float* lB   = (const float*)d_in[4];
    float* out = (float*)d_out;

    const int  N  = in_sizes[2];                  // d_out = 4096
    const int  Kd = in_sizes[1] / N;              // d_in  = 4096
    const int  r  = in_sizes[4] / N;              // 16
    const long M  = (long)in_sizes[0] / Kd;       // B*S   = 8192

    size_t xb_bytes = (size_t)M * Kd * sizeof(bf16s);
    size_t wb_bytes = (size_t)N * Kd * sizeof(bf16s);

    if (ws_size >= xb_bytes + wb_bytes &&
        (M % BM) == 0 && (N % BN) == 0 && (Kd % BK) == 0) {
        bf16s* xb = (bf16s*)d_ws;
        bf16s* wb = (bf16s*)((char*)d_ws + xb_bytes);

        long n4 = (long)M * Kd / 4;
        cvt_f32_bf16<<<2048, 256, 0, stream>>>(x, xb, n4);

        long total_w = (long)N * (Kd / 4);
        int blk_w = (int)((total_w + 255) / 256);
        adjust_weight<<<blk_w, 256, 0, stream>>>(W, lA, lB, wb, N, Kd, r);

        int grid = (int)(M / BM) * (N / BN);
        gemm_2blk<<<grid, 512, 0, stream>>>(xb, wb, bias, out, (int)M, N, Kd);
    } else {
        // f32 fallback: xa = x @ lA^T  (M x r), then naive out
        float* xa = (float*)d_ws;   // needs M*r*4 bytes = 512 KB
        long total_xa = M * (long)r;
        int blk_xa = (int)((total_xa + 255) / 256);
        xa_kernel<<<blk_xa, 256, 0, stream>>>(x, lA, xa, M, Kd, r);
        long total_o = M * (long)N;
        int blk_o = (int)((total_o + 255) / 256);
        naive_out<<<blk_o, 256, 0, stream>>>(x, W, bias, xa, lB, out, M, N, Kd, r);
    }
}

// Round 9
// 316.368 us; speedup vs baseline: 8.5422x; 8.5422x over previous
//
#include <hip/hip_runtime.h>
#include <hip/hip_bf16.h>
#include <stdint.h>

typedef __hip_bfloat16 bf16s;                                    // storage type
typedef __bf16 bf16x8 __attribute__((ext_vector_type(8)));       // MFMA operand
typedef float  floatx4 __attribute__((ext_vector_type(4)));      // MFMA acc

#define BM 256
#define BN 256
#define BK 64

__device__ __forceinline__ void gload_lds16(const void* g, void* l) {
    auto* gp = reinterpret_cast<const __attribute__((address_space(1))) uint32_t*>(
        reinterpret_cast<uintptr_t>(g));
    auto* lp = reinterpret_cast<__attribute__((address_space(3))) uint32_t*>(
        reinterpret_cast<uintptr_t>(l));
    __builtin_amdgcn_global_load_lds(gp, lp, 16, 0, 0);
}

// ---------- x (f32) -> bf16, vectorized ----------
__global__ void cvt_f32_bf16(const float* __restrict__ x, bf16s* __restrict__ y, long n4) {
    long i = (long)blockIdx.x * blockDim.x + threadIdx.x;
    long stride = (long)gridDim.x * blockDim.x;
    for (; i < n4; i += stride) {
        float4 v = ((const float4*)x)[i];
        bf16s tmp[4];
        tmp[0] = __float2bfloat16(v.x);
        tmp[1] = __float2bfloat16(v.y);
        tmp[2] = __float2bfloat16(v.z);
        tmp[3] = __float2bfloat16(v.w);
        *(uint2*)&y[i * 4] = *(uint2*)tmp;
    }
}

// ---------- Wadj = W + lora_B @ lora_A, output bf16 ----------
__global__ void adjust_weight(const float* __restrict__ W, const float* __restrict__ lA,
                              const float* __restrict__ lB, bf16s* __restrict__ Wb,
                              int N, int Kd, int r) {
    long idx = (long)blockIdx.x * blockDim.x + threadIdx.x;
    int kq = Kd >> 2;
    long total = (long)N * kq;
    if (idx >= total) return;
    int n  = (int)(idx / kq);
    int k4 = (int)(idx - (long)n * kq) << 2;
    float4 w = *(const float4*)&W[(size_t)n * Kd + k4];
    float a0 = w.x, a1 = w.y, a2 = w.z, a3 = w.w;
    for (int j = 0; j < r; ++j) {
        float b = lB[n * r + j];
        float4 av = *(const float4*)&lA[(size_t)j * Kd + k4];
        a0 += b * av.x; a1 += b * av.y; a2 += b * av.z; a3 += b * av.w;
    }
    bf16s tmp[4];
    tmp[0] = __float2bfloat16(a0);
    tmp[1] = __float2bfloat16(a1);
    tmp[2] = __float2bfloat16(a2);
    tmp[3] = __float2bfloat16(a3);
    *(uint2*)&Wb[(size_t)n * Kd + k4] = *(uint2*)tmp;
}

// ==========================================================================
// m201-faithful 8-phase schedule: 256x256 tile, BK=64, 8 waves (2M x 4N),
// 2 K-tiles per iteration (u=buf0, v=buf1). Per phase:
//   {ds_reads (12/4/0/8 pattern) | stage 1 half-tile (2 gload_lds)
//    -> barrier -> 16 MFMA -> barrier}
// vmcnt(6) ONLY at phases 4 and 8 (3 half-tiles = 6 loads stay in flight).
// Stage order: ph1 A1(v), ph2 A0(u+2), ph3 B0(u+2), ph4 B1(u+2),
//              ph5 A1(u+2), ph6 A0(v+2), ph7 B0(v+2), ph8 B1(v+2).
// Audited ledger: wait@ph4 retires tile v fully (read ph5-8); wait@ph8
// retires tile u+2 (read next ph1-4). Every in-flight DMA write region is
// disjoint from every concurrently-read LDS region (WAR/race-free; each
// stage targets a region whose last ds_read completed >=1 barrier earlier).
// Uniform clamped tail; vmcnt(0) drain before epilogue.
// Staging/swizzle/epilogue byte-identical to r4 (verified correct, 0 bank
// conflicts): LDS slot s of row l holds source granule s^(l&7).
// ==========================================================================
__global__ __launch_bounds__(512, 2)
void gemm_m201(const bf16s* __restrict__ A,   // [M,K] bf16
               const bf16s* __restrict__ B,   // [N,K] bf16
               const float* __restrict__ bias,
               float* __restrict__ C,         // [M,N] f32
               int M, int N, int K) {
    __shared__ __align__(16) bf16s lds[2][2][BM * BK];   // [dbuf][A=0/B=1] 128 KiB

    const int nbn = N / BN;
    const int nwg = gridDim.x;
    int bid = blockIdx.x;
    int swz = bid;
    if ((nwg & 7) == 0) swz = (bid & 7) * (nwg >> 3) + (bid >> 3);   // XCD swizzle
    const int bm = swz / nbn, bn = swz % nbn;

    const int th   = threadIdx.x;
    const int lane = th & 63;
    const int wid  = th >> 6;
    const int wm = wid >> 2;           // 0..1 -> 128-row slice
    const int wn = wid & 3;            // 0..3 -> 64-col slice
    const int lr = lane & 15;
    const int kg = lane >> 4;          // 16B granule group along K

    const bf16s* gA = A + (size_t)(bm * BM) * K;
    const bf16s* gB = B + (size_t)(bn * BN) * K;
    const int NT  = K / BK;            // 64
    const int NIT = NT / 2;            // 32

    floatx4 acc[8][4];
#pragma unroll
    for (int m = 0; m < 8; ++m)
#pragma unroll
        for (int n = 0; n < 4; ++n)
            acc[m][n] = (floatx4){0.f, 0.f, 0.f, 0.f};

    const int trow = th >> 3;                       // 0..63 rows per G-load
    const int tgr  = (th & 7) ^ (trow & 7);         // pre-swizzled src granule

    auto stageA = [&](int dbuf, int mh, int k0) {
#pragma unroll
        for (int g = 0; g < 2; ++g) {
            int p = g * 128 + mh * 64 + trow;       // phys A row
            gload_lds16(gA + (size_t)p * K + k0 + tgr * 8,
                        &lds[dbuf][0][(mh * 128 + g * 64) * BK + th * 8]);
        }
    };
    auto stageB = [&](int dbuf, int nh, int k0) {
#pragma unroll
        for (int g = 0; g < 2; ++g) {
            int rest = g * 64 + trow;               // 0..127
            int p = (rest >> 5) * 64 + nh * 32 + (rest & 31);   // phys B row
            gload_lds16(gB + (size_t)p * K + k0 + tgr * 8,
                        &lds[dbuf][1][(nh * 128 + g * 64) * BK + th * 8]);
        }
    };

    auto ldA = [&](const bf16s* base, int mh, int mp, int kk) -> bf16x8 {
        int l = mh * 128 + wm * 64 + mp * 16 + lr;
        int c = ((kk << 2) | kg) ^ (lr & 7);
        return *(const bf16x8*)(base + l * BK + c * 8);
    };
    auto ldB = [&](const bf16s* base, int nh, int np, int kk) -> bf16x8 {
        int l = nh * 128 + wn * 32 + np * 16 + lr;
        int c = ((kk << 2) | kg) ^ (lr & 7);
        return *(const bf16x8*)(base + l * BK + c * 8);
    };

    bf16x8 a0[4][2], a1[4][2], b0[2][2], b1[2][2];

    auto readA = [&](bf16x8 (&dst)[4][2], const bf16s* base, int mh) {
#pragma unroll
        for (int mp = 0; mp < 4; ++mp)
#pragma unroll
            for (int kk = 0; kk < 2; ++kk)
                dst[mp][kk] = ldA(base, mh, mp, kk);
    };
    auto readB = [&](bf16x8 (&dst)[2][2], const bf16s* base, int nh) {
#pragma unroll
        for (int np = 0; np < 2; ++np)
#pragma unroll
            for (int kk = 0; kk < 2; ++kk)
                dst[np][kk] = ldB(base, nh, np, kk);
    };
    auto mfma16 = [&](int mo, int no, bf16x8 (&a)[4][2], bf16x8 (&b)[2][2]) {
        __builtin_amdgcn_s_setprio(1);
#pragma unroll
        for (int mp = 0; mp < 4; ++mp)
#pragma unroll
            for (int np = 0; np < 2; ++np)
#pragma unroll
                for (int kk = 0; kk < 2; ++kk)
                    acc[mo + mp][no + np] = __builtin_amdgcn_mfma_f32_16x16x32_bf16(
                        a[mp][kk], b[np][kk], acc[mo + mp][no + np], 0, 0, 0);
        __builtin_amdgcn_s_setprio(0);
    };

    const bf16s* Ab0 = &lds[0][0][0];
    const bf16s* Bb0 = &lds[0][1][0];
    const bf16s* Ab1 = &lds[1][0][0];
    const bf16s* Bb1 = &lds[1][1][0];

    // ---- prologue: tile0 (4 halves) + tile1 (3 halves); retire tile0 ----
    stageA(0, 0, 0); stageB(0, 0, 0); stageB(0, 1, 0); stageA(0, 1, 0);
    stageA(1, 0, BK); stageB(1, 0, BK); stageB(1, 1, BK);
    asm volatile("s_waitcnt vmcnt(6)" ::: "memory");
    asm volatile("s_barrier" ::: "memory");

    for (int it = 0; it < NIT; ++it) {
        const int u   = 2 * it;
        const int kv  = (u + 1) * BK;
        const int ku2 = ((u + 2) < NT ? (u + 2) : (NT - 1)) * BK;   // clamped tail
        const int kv2 = ((u + 3) < NT ? (u + 3) : (NT - 1)) * BK;

        // ---- ph1: tile u, quad(mh0,nh0); stage A1(v) ----
        readA(a0, Ab0, 0); readB(b0, Bb0, 0);            // 12 ds_reads
        stageA(1, 1, kv);
        asm volatile("s_waitcnt lgkmcnt(8)" ::: "memory");
        asm volatile("s_barrier" ::: "memory");
        mfma16(0, 0, a0, b0);
        asm volatile("s_barrier" ::: "memory");

        // ---- ph2: quad(mh0,nh1); stage A0(u+2) ----
        readB(b1, Bb0, 1);                               // 4 ds_reads
        stageA(0, 0, ku2);
        asm volatile("s_barrier" ::: "memory");
        mfma16(0, 2, a0, b1);
        asm volatile("s_barrier" ::: "memory");

        // ---- ph3: quad(mh1,nh1); stage B0(u+2) ----
        readA(a1, Ab0, 1);                               // 8 ds_reads
        stageB(0, 0, ku2);
        asm volatile("s_barrier" ::: "memory");
        mfma16(4, 2, a1, b1);
        asm volatile("s_barrier" ::: "memory");

        // ---- ph4: quad(mh1,nh0); stage B1(u+2); WAIT -> tile v landed ----
        stageB(0, 1, ku2);
        asm volatile("s_barrier" ::: "memory");
        mfma16(4, 0, a1, b0);
        asm volatile("s_waitcnt vmcnt(6)" ::: "memory");
        asm volatile("s_barrier" ::: "memory");

        // ---- ph5: tile v, quad(mh0,nh0); stage A1(u+2) ----
        readA(a0, Ab1, 0); readB(b0, Bb1, 0);            // 12 ds_reads
        stageA(0, 1, ku2);
        asm volatile("s_waitcnt lgkmcnt(8)" ::: "memory");
        asm volatile("s_barrier" ::: "memory");
        mfma16(0, 0, a0, b0);
        asm volatile("s_barrier" ::: "memory");

        // ---- ph6: quad(mh0,nh1); stage A0(v+2) ----
        readB(b1, Bb1, 1);
        stageA(1, 0, kv2);
        asm volatile("s_barrier" ::: "memory");
        mfma16(0, 2, a0, b1);
        asm volatile("s_barrier" ::: "memory");

        // ---- ph7: quad(mh1,nh1); stage B0(v+2) ----
        readA(a1, Ab1, 1);
        stageB(1, 0, kv2);
        asm volatile("s_barrier" ::: "memory");
        mfma16(4, 2, a1, b1);
        asm volatile("s_barrier" ::: "memory");

        // ---- ph8: quad(mh1,nh0); stage B1(v+2); WAIT -> tile u+2 landed ----
        stageB(1, 1, kv2);
        asm volatile("s_barrier" ::: "memory");
        mfma16(4, 0, a1, b0);
        asm volatile("s_waitcnt vmcnt(6)" ::: "memory");
        asm volatile("s_barrier" ::: "memory");
    }

    // drain remaining LDS-DMA before s_endpgm
    asm volatile("s_waitcnt vmcnt(0)" ::: "memory");

    // ---- epilogue: C/D layout col = lane&15, row = (lane>>4)*4 + q ----
    const int crow = bm * BM + wm * 128;
    const int ccol = bn * BN + wn * 64;
#pragma unroll
    for (int n = 0; n < 4; ++n) {
        int col = ccol + n * 16 + lr;
        float bv = bias[col];
#pragma unroll
        for (int m = 0; m < 8; ++m) {
            int row0 = crow + m * 16 + kg * 4;
#pragma unroll
            for (int q = 0; q < 4; ++q)
                C[(size_t)(row0 + q) * N + col] = acc[m][n][q] + bv;
        }
    }
}

// ---------- fallback (f32, slow but correct) ----------
__global__ void xa_kernel(const float* __restrict__ x, const float* __restrict__ lA,
                          float* __restrict__ xa, long M, int K, int r) {
    long idx = (long)blockIdx.x * blockDim.x + threadIdx.x;
    long total = M * r;
    if (idx >= total) return;
    long m = idx / r; int j = (int)(idx % r);
    const float* xr = x + m * (long)K;
    const float* ar = lA + (size_t)j * K;
    float s = 0.f;
    for (int k = 0; k < K; k += 4) {
        float4 xv = *(const float4*)&xr[k];
        float4 av = *(const float4*)&ar[k];
        s += xv.x * av.x + xv.y * av.y + xv.z * av.z + xv.w * av.w;
    }
    xa[idx] = s;
}

__global__ void naive_out(const float* __restrict__ x, const float* __restrict__ W,
                          const float* __restrict__ bias, const float* __restrict__ xa,
                          const float* __restrict__ lB, float* __restrict__ out,
                          long M, int N, int K, int r) {
    long idx = (long)blockIdx.x * blockDim.x + threadIdx.x;
    long total = M * (long)N;
    if (idx >= total) return;
    long m = idx / N; int n = (int)(idx % N);
    const float* xr = x + m * (long)K;
    const float* wr = W + (size_t)n * K;
    float s = bias[n];
    for (int k = 0; k < K; k += 4) {
        float4 xv = *(const float4*)&xr[k];
        float4 wv = *(const float4*)&wr[k];
        s += xv.x * wv.x + xv.y * wv.y + xv.z * wv.z + xv.w * wv.w;
    }
    const float* xar = xa + m * r;
    const float* br  = lB + (size_t)n * r;
    for (int j = 0; j < r; ++j) s += xar[j] * br[j];
    out[idx] = s;
}

extern "C" void kernel_launch(void* const* d_in, const int* in_sizes, int n_in,
                              void* d_out, int out_size, void* d_ws, size_t ws_size,
                              hipStream_t stream) {
    const float* x    = (const float*)d_in[0];
    const float* W    = (const float*)d_in[1];
    const float* bias = (const float*)d_in[2];
    const float* lA   = (const float*)d_in[3];
    const float* lB   = (const float*)d_in[4];
    float* out = (float*)d_out;

    const int  N  = in_sizes[2];                  // d_out = 4096
    const int  Kd = in_sizes[1] / N;              // d_in  = 4096
    const int  r  = in_sizes[4] / N;              // 16
    const long M  = (long)in_sizes[0] / Kd;       // B*S   = 8192

    size_t xb_bytes = (size_t)M * Kd * sizeof(bf16s);
    size_t wb_bytes = (size_t)N * Kd * sizeof(bf16s);

    const int NTv = Kd / BK;
    if (ws_size >= xb_bytes + wb_bytes &&
        (M % BM) == 0 && (N % BN) == 0 && (Kd % BK) == 0 &&
        NTv >= 4 && (NTv % 2) == 0) {
        bf16s* xb = (bf16s*)d_ws;
        bf16s* wb = (bf16s*)((char*)d_ws + xb_bytes);

        long n4 = (long)M * Kd / 4;
        cvt_f32_bf16<<<2048, 256, 0, stream>>>(x, xb, n4);

        long total_w = (long)N * (Kd / 4);
        int blk_w = (int)((total_w + 255) / 256);
        adjust_weight<<<blk_w, 256, 0, stream>>>(W, lA, lB, wb, N, Kd, r);

        int grid = (int)(M / BM) * (N / BN);
        gemm_m201<<<grid, 512, 0, stream>>>(xb, wb, bias, out, (int)M, N, Kd);
    } else {
        // f32 fallback: xa = x @ lA^T  (M x r), then naive out
        float* xa = (float*)d_ws;   // needs M*r*4 bytes = 512 KB
        long total_xa = M * (long)r;
        int blk_xa = (int)((total_xa + 255) / 256);
        xa_kernel<<<blk_xa, 256, 0, stream>>>(x, lA, xa, M, Kd, r);
        long total_o = M * (long)N;
        int blk_o = (int)((total_o + 255) / 256);
        naive_out<<<blk_o, 256, 0, stream>>>(x, W, bias, xa, lB, out, M, N, Kd, r);
    }
}